// Round 32
// baseline (260.907 us; speedup 1.0000x reference)
//
#include <hip/hip_runtime.h>
#include <cmath>
#include <stdint.h>

#pragma clang fp contract(off)

// Register barrier: isolates each FP op (no contraction/reassociation).
__device__ __forceinline__ void opqf(float& v) { asm volatile("" : "+v"(v)); }

__device__ __forceinline__ uint32_t fbits(float f) { return __float_as_uint(f); }
__device__ __forceinline__ float bitsf(uint32_t u) { return __uint_as_float(u); }

// Correctly-rounded f32 divide (a>=0, b>0 normal), flag-proof (integer-verified).
__device__ __forceinline__ uint32_t soft_div(uint32_t ab, uint32_t bb) {
    if ((ab & 0x7fffffffu) == 0u) return 0u;
    int ea = (int)((ab >> 23) & 0xffu), eb = (int)((bb >> 23) & 0xffu);
    uint64_t ma = (uint64_t)((ab & 0x7fffffu) | 0x800000u);
    uint64_t mb = (uint64_t)((bb & 0x7fffffu) | 0x800000u);
    uint64_t n = ma << 31;
    uint64_t q = (uint64_t)((double)n / (double)mb);
    int64_t r = (int64_t)(n - q * mb);
    while (r < 0)            { --q; r += (int64_t)mb; }
    while (r >= (int64_t)mb) { ++q; r -= (int64_t)mb; }
    int e = ea - eb + 127;
    int shift = (q >= (1ull << 31)) ? 8 : 7;
    if (shift == 7) e -= 1;
    uint32_t q32 = (uint32_t)q;
    uint32_t mant = (uint32_t)(q >> shift);
    uint32_t below = q32 & ((1u << shift) - 1u);
    uint32_t rb = (below >> (shift - 1)) & 1u;
    uint32_t sticky = ((r != 0) | (below & ((1u << (shift - 1)) - 1u))) ? 1u : 0u;
    mant += (rb & (sticky | (mant & 1u)));
    if (mant >> 24) { mant >>= 1; e += 1; }
    return ((uint32_t)e << 23) | (mant & 0x7fffffu);
}

// Correctly-rounded f32 sqrt (x>0 normal), flag-proof (integer-verified).
__device__ __forceinline__ uint32_t soft_sqrt(uint32_t xb) {
    int ue = (int)((xb >> 23) & 0xffu) - 127;
    uint64_t mx = (uint64_t)((xb & 0x7fffffu) | 0x800000u);
    uint64_t N = mx << (23 + (ue & 1));
    uint64_t s = (uint64_t)__builtin_sqrt((double)N);
    while (s * s > N) --s;
    while ((s + 1) * (s + 1) <= N) ++s;
    uint64_t mant = s + ((N > s * (s + 1)) ? 1u : 0u);
    int e = (ue >> 1) + 127;
    if (mant >> 24) { mant >>= 1; e += 1; }
    return ((uint32_t)e << 23) | ((uint32_t)mant & 0x7fffffu);
}

// combos = sorted(itertools.combinations(range(8), 2))
__device__ __constant__ int d_CI[28] = {0,0,0,0,0,0,0,1,1,1,1,1,1,2,2,2,2,2,3,3,3,3,4,4,4,5,5,6};
__device__ __constant__ int d_CJ[28] = {1,2,3,4,5,6,7,2,3,4,5,6,7,3,4,5,6,7,4,5,6,7,5,6,7,6,7,7};
__device__ __constant__ int d_CM[28] = {3,5,9,17,33,65,129,6,10,18,34,66,130,12,20,36,68,132,24,40,72,136,48,80,144,96,160,192};

__global__ __launch_bounds__(256) void mass_asym_kernel(const float* __restrict__ x,
                                                        float* __restrict__ out,
                                                        int n) {
#pragma clang fp contract(off)
    __shared__ float sm[256 * 29];                      // stride 29: conflict-free
    int t = blockIdx.x * blockDim.x + threadIdx.x;
    if (t >= n) return;

    constexpr int CI[28] = {0,0,0,0,0,0,0,1,1,1,1,1,1,2,2,2,2,2,3,3,3,3,4,4,4,5,5,6};
    constexpr int CJ[28] = {1,2,3,4,5,6,7,2,3,4,5,6,7,3,4,5,6,7,4,5,6,7,5,6,7,6,7,7};

    const float4* xp = reinterpret_cast<const float4*>(x) + (size_t)t * 8;
    float E[8], px[8], py[8], pz[8];
#pragma unroll
    for (int i = 0; i < 8; ++i) {
        float4 v = xp[i];
        E[i] = v.x; px[i] = v.y; py[i] = v.z; pz[i] = v.w;
    }

    float* myrow = &sm[threadIdx.x * 29];

    // THIS ROUND — 2-ACCUMULATOR BLAS-sdot cell:
    //   acc0 = a*a                  (bare, rounds)
    //   acc1 = b*b                  (bare, rounds)
    //   acc0 = fma(d,d, acc0)       (tail element fused onto acc0)
    //   s    = acc0 + acc1          (plain combining add, rounds)
    //   e2   = e*e                  (rounds)
    //   m2   = e2 - s               (plain subtract, rounds)
    //   m    = CR f32 sqrt
#pragma unroll
    for (int c = 0; c < 28; ++c) {
        float e = E[CI[c]]  + E[CJ[c]];  opqf(e);
        float a = px[CI[c]] + px[CJ[c]]; opqf(a);
        float b = py[CI[c]] + py[CJ[c]]; opqf(b);
        float d = pz[CI[c]] + pz[CJ[c]]; opqf(d);
        float acc0 = a * a; opqf(acc0);             // bare px^2
        float acc1 = b * b; opqf(acc1);             // bare py^2
        acc0 = __builtin_fmaf(d, d, acc0); opqf(acc0); // + pz^2 (fused)
        float s = acc0 + acc1; opqf(s);             // plain combining add
        float e2 = e * e; opqf(e2);                 // e^2 (rounds)
        float m2 = e2 - s; opqf(m2);                // plain subtract (rounds)
        myrow[c] = bitsf(soft_sqrt(fbits(m2)));
    }

    // 210 disjoint pairs, lexicographic PAIRS order; integer bit-compare of
    // positive floats; strict < = first-min (np.argmin tie-break).
    uint32_t ubest = 0x7f800000u;   // +inf
    uint32_t ubma = 0u, ubmb = 0u;
    int bpack = 0;
#pragma unroll 1
    for (int a = 0; a < 27; ++a) {
        const int cma = d_CM[a];
#pragma unroll 1
        for (int b = a + 1; b < 28; ++b) {
            if (cma & d_CM[b]) continue;
            float va = myrow[a], vb = myrow[b];
            float diff = va - vb; opqf(diff);
            float num = fabsf(diff);
            float den = va + vb; opqf(den);
            uint32_t uv = soft_div(fbits(num), fbits(den));
            bool better = uv < ubest;
            ubest = better ? uv : ubest;
            ubma  = better ? fbits(va) : ubma;
            ubmb  = better ? fbits(vb) : ubmb;
            bpack = better ? (a * 32 + b) : bpack;
        }
    }

    const int ba = bpack >> 5;
    const int bb = bpack & 31;

    float* o = out + (size_t)t * 7;
    o[0] = (float)d_CI[ba];
    o[1] = (float)d_CJ[ba];
    o[2] = (float)d_CI[bb];
    o[3] = (float)d_CJ[bb];
    o[4] = bitsf(ubma);
    o[5] = bitsf(ubmb);
    o[6] = bitsf(ubest);
}

extern "C" void kernel_launch(void* const* d_in, const int* in_sizes, int n_in,
                              void* d_out, int out_size, void* d_ws, size_t ws_size,
                              hipStream_t stream) {
    const float* x = (const float*)d_in[0];
    float* out = (float*)d_out;
    const int n = in_sizes[0] / 32;          // events
    const int block = 256;
    const int grid = (n + block - 1) / block;
    mass_asym_kernel<<<grid, block, 0, stream>>>(x, out, n);
}

// Round 33
// 97.310 us; speedup vs baseline: 2.6812x; 2.6812x over previous
//
#include <hip/hip_runtime.h>
#include <cmath>
#include <stdint.h>

#pragma clang fp contract(off)

// Register barrier: isolates each FP op (no contraction/reassociation).
__device__ __forceinline__ void opqf(float& v) { asm volatile("" : "+v"(v)); }

__device__ __forceinline__ uint32_t fbits(float f) { return __float_as_uint(f); }
__device__ __forceinline__ float bitsf(uint32_t u) { return __uint_as_float(u); }

// combos = sorted(itertools.combinations(range(8), 2))
__device__ __constant__ int d_CI[28] = {0,0,0,0,0,0,0,1,1,1,1,1,1,2,2,2,2,2,3,3,3,3,4,4,4,5,5,6};
__device__ __constant__ int d_CJ[28] = {1,2,3,4,5,6,7,2,3,4,5,6,7,3,4,5,6,7,4,5,6,7,5,6,7,6,7,7};
__device__ __constant__ int d_CM[28] = {3,5,9,17,33,65,129,6,10,18,34,66,130,12,20,36,68,132,24,40,72,136,48,80,144,96,160,192};

__global__ __launch_bounds__(256) void mass_asym_kernel(const float* __restrict__ x,
                                                        float* __restrict__ out,
                                                        int n) {
#pragma clang fp contract(off)
    __shared__ float sm[256 * 29];                      // stride 29: conflict-free
    int t = blockIdx.x * blockDim.x + threadIdx.x;
    if (t >= n) return;

    constexpr int CI[28] = {0,0,0,0,0,0,0,1,1,1,1,1,1,2,2,2,2,2,3,3,3,3,4,4,4,5,5,6};
    constexpr int CJ[28] = {1,2,3,4,5,6,7,2,3,4,5,6,7,3,4,5,6,7,4,5,6,7,5,6,7,6,7,7};

    const float4* xp = reinterpret_cast<const float4*>(x) + (size_t)t * 8;
    float E[8], px[8], py[8], pz[8];
#pragma unroll
    for (int i = 0; i < 8; ++i) {
        float4 v = xp[i];
        E[i] = v.x; px[i] = v.y; py[i] = v.z; pz[i] = v.w;
    }

    float* myrow = &sm[threadIdx.x * 29];

    // PROVEN REFERENCE PIPELINE (R32, passed absmax 4.5):
    //   acc0 = a*a; acc1 = b*b; acc0 = fma(d,d,acc0); s = acc0+acc1
    //   e2 = e*e; m2 = e2 - s;  m = CR f32 sqrt (HW, correctly rounded)
    // HW sqrtf/div proven CR by R1===R2===R6 fingerprint identity.
#pragma unroll
    for (int c = 0; c < 28; ++c) {
        float e = E[CI[c]]  + E[CJ[c]];  opqf(e);
        float a = px[CI[c]] + px[CJ[c]]; opqf(a);
        float b = py[CI[c]] + py[CJ[c]]; opqf(b);
        float d = pz[CI[c]] + pz[CJ[c]]; opqf(d);
        float acc0 = a * a; opqf(acc0);             // bare px^2
        float acc1 = b * b; opqf(acc1);             // bare py^2
        acc0 = __builtin_fmaf(d, d, acc0); opqf(acc0); // + pz^2 (fused)
        float s = acc0 + acc1; opqf(s);             // plain combining add
        float e2 = e * e; opqf(e2);                 // e^2 (rounds)
        float m2 = e2 - s; opqf(m2);                // plain subtract (rounds)
        myrow[c] = sqrtf(m2);                       // HW CR f32 sqrt
    }

    // 210 disjoint pairs, lexicographic PAIRS order; HW CR f32 divide;
    // integer bit-compare of positive floats; strict < = first-min.
    uint32_t ubest = 0x7f800000u;   // +inf
    uint32_t ubma = 0u, ubmb = 0u;
    int bpack = 0;
#pragma unroll 1
    for (int a = 0; a < 27; ++a) {
        const int cma = d_CM[a];
#pragma unroll 1
        for (int b = a + 1; b < 28; ++b) {
            if (cma & d_CM[b]) continue;
            float va = myrow[a], vb = myrow[b];
            float num = fabsf(va - vb);             // sub+abs: exact IEEE ops
            float den = va + vb;                    // exact IEEE add
            float v = num / den;                    // HW CR f32 divide
            uint32_t uv = fbits(v);
            bool better = uv < ubest;
            ubest = better ? uv : ubest;
            ubma  = better ? fbits(va) : ubma;
            ubmb  = better ? fbits(vb) : ubmb;
            bpack = better ? (a * 32 + b) : bpack;
        }
    }

    const int ba = bpack >> 5;
    const int bb = bpack & 31;

    float* o = out + (size_t)t * 7;
    o[0] = (float)d_CI[ba];
    o[1] = (float)d_CJ[ba];
    o[2] = (float)d_CI[bb];
    o[3] = (float)d_CJ[bb];
    o[4] = bitsf(ubma);
    o[5] = bitsf(ubmb);
    o[6] = bitsf(ubest);
}

extern "C" void kernel_launch(void* const* d_in, const int* in_sizes, int n_in,
                              void* d_out, int out_size, void* d_ws, size_t ws_size,
                              hipStream_t stream) {
    const float* x = (const float*)d_in[0];
    float* out = (float*)d_out;
    const int n = in_sizes[0] / 32;          // events
    const int block = 256;
    const int grid = (n + block - 1) / block;
    mass_asym_kernel<<<grid, block, 0, stream>>>(x, out, n);
}

// Round 34
// 66.047 us; speedup vs baseline: 3.9503x; 1.4733x over previous
//
#include <hip/hip_runtime.h>
#include <cmath>
#include <stdint.h>

#pragma clang fp contract(off)

// Register barrier: isolates each FP op (no contraction/reassociation).
// Used ONLY in the m^2 block (the contraction-sensitive part).
__device__ __forceinline__ void opqf(float& v) { asm volatile("" : "+v"(v)); }

__device__ __forceinline__ uint32_t fbits(float f) { return __float_as_uint(f); }
__device__ __forceinline__ float bitsf(uint32_t u) { return __uint_as_float(u); }

// combos = sorted(itertools.combinations(range(8), 2))
__device__ __constant__ int d_CI[28] = {0,0,0,0,0,0,0,1,1,1,1,1,1,2,2,2,2,2,3,3,3,3,4,4,4,5,5,6};
__device__ __constant__ int d_CJ[28] = {1,2,3,4,5,6,7,2,3,4,5,6,7,3,4,5,6,7,4,5,6,7,5,6,7,6,7,7};

__global__ __launch_bounds__(256) void mass_asym_kernel(const float* __restrict__ x,
                                                        float* __restrict__ out,
                                                        int n) {
#pragma clang fp contract(off)
    int t = blockIdx.x * blockDim.x + threadIdx.x;
    if (t >= n) return;

    constexpr int CI[28] = {0,0,0,0,0,0,0,1,1,1,1,1,1,2,2,2,2,2,3,3,3,3,4,4,4,5,5,6};
    constexpr int CJ[28] = {1,2,3,4,5,6,7,2,3,4,5,6,7,3,4,5,6,7,4,5,6,7,5,6,7,6,7,7};

    const float4* xp = reinterpret_cast<const float4*>(x) + (size_t)t * 8;
    float E[8], px[8], py[8], pz[8];
#pragma unroll
    for (int i = 0; i < 8; ++i) {
        float4 v = xp[i];
        E[i] = v.x; px[i] = v.y; py[i] = v.z; pz[i] = v.w;
    }

    // PROVEN REFERENCE PIPELINE (R32/R33, passed absmax 4.5):
    //   acc0 = a*a; acc1 = b*b; acc0 = fma(d,d,acc0); s = acc0+acc1
    //   e2 = e*e; m2 = e2 - s;  m = HW CR f32 sqrt
    // Masses stay in REGISTERS (static indices after full unroll).
    float m[28];
#pragma unroll
    for (int c = 0; c < 28; ++c) {
        float e = E[CI[c]]  + E[CJ[c]];  opqf(e);
        float a = px[CI[c]] + px[CJ[c]]; opqf(a);
        float b = py[CI[c]] + py[CJ[c]]; opqf(b);
        float d = pz[CI[c]] + pz[CJ[c]]; opqf(d);
        float acc0 = a * a; opqf(acc0);             // bare px^2
        float acc1 = b * b; opqf(acc1);             // bare py^2
        acc0 = __builtin_fmaf(d, d, acc0); opqf(acc0); // + pz^2 (fused)
        float s = acc0 + acc1; opqf(s);             // plain combining add
        float e2 = e * e; opqf(e2);                 // e^2 (rounds)
        float m2 = e2 - s; opqf(m2);                // plain subtract (rounds)
        m[c] = sqrtf(m2);                           // HW CR f32 sqrt
    }

    // 210 disjoint pairs, FULLY UNROLLED, lexicographic PAIRS order.
    // Same IEEE op sequence as R33 (sub, abs, add, CR divide) -> identical
    // selection. Track only best-bits + packed index (2 cndmask/pair).
    uint32_t ubest = 0x7f800000u;   // +inf
    int bpack = 0;
#pragma unroll
    for (int a = 0; a < 28; ++a) {
#pragma unroll
        for (int b = a + 1; b < 28; ++b) {
            constexpr unsigned MA[28] = {3,5,9,17,33,65,129,6,10,18,34,66,130,12,20,36,68,132,24,40,72,136,48,80,144,96,160,192};
            if ((MA[a] & MA[b]) != 0u) continue;    // folds at compile time
            float num = fabsf(m[a] - m[b]);         // exact IEEE sub+abs
            float den = m[a] + m[b];                // exact IEEE add
            float v = num / den;                    // HW CR f32 divide
            uint32_t uv = fbits(v);
            bool better = uv < ubest;
            ubest = better ? uv : ubest;
            bpack = better ? (a * 32 + b) : bpack;
        }
    }

    const int ba = bpack >> 5;
    const int bb = bpack & 31;

    // Decode the two selected masses from registers via cndmask tree.
    float bma = m[0], bmb = m[0];
#pragma unroll
    for (int i = 1; i < 28; ++i) {
        bma = (ba == i) ? m[i] : bma;
        bmb = (bb == i) ? m[i] : bmb;
    }

    float* o = out + (size_t)t * 7;
    o[0] = (float)d_CI[ba];
    o[1] = (float)d_CJ[ba];
    o[2] = (float)d_CI[bb];
    o[3] = (float)d_CJ[bb];
    o[4] = bma;
    o[5] = bmb;
    o[6] = bitsf(ubest);
}

extern "C" void kernel_launch(void* const* d_in, const int* in_sizes, int n_in,
                              void* d_out, int out_size, void* d_ws, size_t ws_size,
                              hipStream_t stream) {
    const float* x = (const float*)d_in[0];
    float* out = (float*)d_out;
    const int n = in_sizes[0] / 32;          // events
    const int block = 256;
    const int grid = (n + block - 1) / block;
    mass_asym_kernel<<<grid, block, 0, stream>>>(x, out, n);
}